// Round 2
// baseline (420.043 us; speedup 1.0000x reference)
//
#include <hip/hip_runtime.h>

#define QLEN 1024
#define KLEN 2048   // MLEN + QLEN
#define BSZ 4
#define NHEAD 8

static constexpr float INV2PI = 0.15915494309189535f;

// ---------------------------------------------------------------------------
// Fused projection + sincos precompute.
// Blocks [0,128): Q side (4096 rows of h @ Wq). Blocks [128,384): K side
// (8192 rows of concat(mems,h) @ Wk). For each projected value p we store
// {p, sin(R*p), cos(R*p)} into a float4-friendly layout:
//   float4 index = (tok*12 + part*4 + (d>>2))*32 + bh,  part in {0=p,1=s,2=c}
//   (element offset within float4 = d&3;  bh = b*8 + h)
// ---------------------------------------------------------------------------
__global__ __launch_bounds__(256) void fa_proj_kernel(
    const float* __restrict__ h, const float* __restrict__ mems,
    const float* __restrict__ Wq, const float* __restrict__ Wk,
    const float* __restrict__ paramR,
    float* __restrict__ Rq3, float* __restrict__ Rk3)
{
    __shared__ float inT[128 * 36];   // [e][row], stride 36
    const int tid  = threadIdx.x;
    const bool isQ = blockIdx.x < 128;
    const int  blk = isQ ? blockIdx.x : blockIdx.x - 128;
    const int row0 = blk * 32;
    const float* W   = isQ ? Wq : Wk;
    float*      out3 = isQ ? Rq3 : Rk3;

    for (int idx = tid; idx < 32 * 128; idx += 256) {
        int r = idx >> 7;
        int e = idx & 127;
        int grow = row0 + r;
        float v;
        if (isQ)               v = h[(size_t)grow * 128 + e];
        else if (grow < 4096)  v = mems[(size_t)grow * 128 + e];
        else                   v = h[(size_t)(grow - 4096) * 128 + e];
        inT[e * 36 + r] = v;
    }
    __syncthreads();

    const int col  = tid & 127;
    const int half = tid >> 7;

    float acc[16];
#pragma unroll
    for (int j = 0; j < 16; ++j) acc[j] = 0.0f;

#pragma unroll 2
    for (int e = 0; e < 128; ++e) {
        float w = W[e * 128 + col];
        const float4* ap = reinterpret_cast<const float4*>(&inT[e * 36 + half * 16]);
        float4 a0 = ap[0], a1 = ap[1], a2 = ap[2], a3 = ap[3];
        float av[16];
        av[0]=a0.x; av[1]=a0.y; av[2]=a0.z; av[3]=a0.w;
        av[4]=a1.x; av[5]=a1.y; av[6]=a1.z; av[7]=a1.w;
        av[8]=a2.x; av[9]=a2.y; av[10]=a2.z; av[11]=a2.w;
        av[12]=a3.x; av[13]=a3.y; av[14]=a3.z; av[15]=a3.w;
#pragma unroll
        for (int j = 0; j < 16; ++j) acc[j] = fmaf(av[j], w, acc[j]);
    }

    const int hh = col >> 4;        // head
    const int d  = col & 15;
    const float Rrev = paramR[hh] * INV2PI;

#pragma unroll
    for (int j = 0; j < 16; ++j) {
        int r   = row0 + half * 16 + j;
        int tok = r >> 2;
        int b   = r & 3;
        int bh  = b * 8 + hh;
        float p = acc[j];
        float s = __builtin_amdgcn_sinf(Rrev * p);   // sin(R*p)
        float c = __builtin_amdgcn_cosf(Rrev * p);   // cos(R*p)
        int base = ((tok * 12 + (d >> 2)) * 32 + bh) * 4 + (d & 3);
        out3[base]        = p;
        out3[base + 512]  = s;   // part 1: +4 float4-chunks*32*4 floats
        out3[base + 1024] = c;   // part 2
    }
}

// ---------------------------------------------------------------------------
// Main: out[q][k][b][h] = | (prod_d n_d) / (prod_d u_d) |
//   u_d = pq_d - pk_d   (raw diffs)
//   n_d = sin(R*pq)cos(R*pk) - cos(R*pq)sin(R*pk) = sin(R*u_d)  (identity)
// One rcp per output (raw 16-product never under/overflows, 18-sigma).
// Guard: min_d |u_d| < 1e-5 -> cold path (per-d: |u|<1e-5 -> factor = R),
// matching ref's EPS=1e-6 semantics and fencing cancellation noise.
// lanes = (qq 0..7, bh 0..31); q-state in 48 regs; k streamed.
// y = bid&7 selects the 256-wide k-chunk -> per-XCD L2-resident Rk slice.
// ---------------------------------------------------------------------------
__global__ __launch_bounds__(256, 4) void fa_fourier_main(
    const float* __restrict__ Rq3, const float* __restrict__ Rk3,
    const float* __restrict__ paramR, float* __restrict__ out)
{
    const int tid = threadIdx.x;
    const int bh  = tid & 31;          // b*8 + h
    const int qq  = tid >> 5;          // 0..7
    const int bid = blockIdx.x;
    const int y   = bid & 7;           // k-chunk == XCD (round-robin dispatch)
    const int x   = bid >> 3;          // q-block 0..127
    const int q   = x * 8 + qq;
    const int k0  = y * 256;

    const float R = paramR[bh & 7];

    // q-state: 12 float4 = {p[16], s[16], c[16]}
    float4 qv[12];
    const float4* qp = reinterpret_cast<const float4*>(Rq3) + (size_t)q * 384 + bh;
#pragma unroll
    for (int t = 0; t < 12; ++t) qv[t] = qp[t * 32];
    const float* qf = reinterpret_cast<const float*>(&qv[0]);  // qf[0..47]

    const float4* kbase = reinterpret_cast<const float4*>(Rk3) + bh;
    float* outp = out + ((size_t)q * KLEN + k0) * 32 + bh;

    for (int i = 0; i < 256; ++i) {
        const float4* kp = kbase + (size_t)(k0 + i) * 384;
        float4 kv[12];
#pragma unroll
        for (int t = 0; t < 12; ++t) kv[t] = kp[t * 32];
        const float* kf = reinterpret_cast<const float*>(&kv[0]);

        float uu, nn, mn;
#pragma unroll
        for (int c = 0; c < 4; ++c) {
            float u0 = qf[c*4+0] - kf[c*4+0];
            float u1 = qf[c*4+1] - kf[c*4+1];
            float u2 = qf[c*4+2] - kf[c*4+2];
            float u3 = qf[c*4+3] - kf[c*4+3];
            // n_d = sq*ck - cq*sk
            float n0 = fmaf(qf[16+c*4+0], kf[32+c*4+0], -(qf[32+c*4+0] * kf[16+c*4+0]));
            float n1 = fmaf(qf[16+c*4+1], kf[32+c*4+1], -(qf[32+c*4+1] * kf[16+c*4+1]));
            float n2 = fmaf(qf[16+c*4+2], kf[32+c*4+2], -(qf[32+c*4+2] * kf[16+c*4+2]));
            float n3 = fmaf(qf[16+c*4+3], kf[32+c*4+3], -(qf[32+c*4+3] * kf[16+c*4+3]));
            float uq = (u0 * u1) * (u2 * u3);
            float nq = (n0 * n1) * (n2 * n3);
            float mq = fminf(fminf(fabsf(u0), fabsf(u1)), fminf(fabsf(u2), fabsf(u3)));
            if (c == 0) { uu = uq; nn = nq; mn = mq; }
            else        { uu *= uq; nn *= nq; mn = fminf(mn, mq); }
        }

        float r;
        if (__builtin_expect(mn < 1e-5f, 0)) {
            // cold: recompute with ref's small-diff semantics (factor = R)
            float uuc = 1.0f, nnc = 1.0f;
#pragma unroll
            for (int dd = 0; dd < 16; ++dd) {
                float ud = qf[dd] - kf[dd];
                float nd = fmaf(qf[16+dd], kf[32+dd], -(qf[32+dd] * kf[16+dd]));
                if (fabsf(ud) < 1e-5f) { ud = 1.0f; nd = R; }
                uuc *= ud; nnc *= nd;
            }
            if (fabsf(uuc) < 1e-37f) uuc = (uuc < 0.0f) ? -1e-37f : 1e-37f;
            r = nnc * __builtin_amdgcn_rcpf(uuc);
        } else {
            r = nn * __builtin_amdgcn_rcpf(uu);
        }
        __builtin_nontemporal_store(fabsf(r), outp + (size_t)i * 32);
    }
}

extern "C" void kernel_launch(void* const* d_in, const int* in_sizes, int n_in,
                              void* d_out, int out_size, void* d_ws, size_t ws_size,
                              hipStream_t stream)
{
    const float* h    = (const float*)d_in[0];   // [1024,4,128]
    const float* mems = (const float*)d_in[1];   // [1024,4,128]
    const float* Wq   = (const float*)d_in[2];   // [128,128]
    const float* Wk   = (const float*)d_in[3];   // [128,128]
    const float* R    = (const float*)d_in[4];   // [8]
    float* out = (float*)d_out;                  // [1024,2048,4,8] fp32

    float* Rq3 = (float*)d_ws;                   // 1024*1536 floats (6 MB)
    float* Rk3 = Rq3 + (size_t)1024 * 1536;      // 2048*1536 floats (12 MB)

    // Fused projections + sincos: 128 Q-blocks + 256 K-blocks
    fa_proj_kernel<<<dim3(384), 256, 0, stream>>>(h, mems, Wq, Wk, R, Rq3, Rk3);

    // Main: 1024 blocks; bid&7 = k-chunk (XCD-local), bid>>3 = q-block
    fa_fourier_main<<<dim3(1024), 256, 0, stream>>>(Rq3, Rk3, R, out);
}

// Round 3
// 308.149 us; speedup vs baseline: 1.3631x; 1.3631x over previous
//
#include <hip/hip_runtime.h>

#define QLEN 1024
#define KLEN 2048   // MLEN + QLEN

typedef float f32x2 __attribute__((ext_vector_type(2)));

static constexpr float INV2PI = 0.15915494309189535f;
static constexpr float TGUARD = 3e-5f;

// ---------------------------------------------------------------------------
// Fused projection + sincos precompute (unchanged from round 2, verified).
// Layout per token: float4 index = (tok*12 + part*4 + c)*32 + bh
//   part 0 = p, 1 = sin(R*p), 2 = cos(R*p);  c = d>>2;  elem = d&3
// ---------------------------------------------------------------------------
__global__ __launch_bounds__(256) void fa_proj_kernel(
    const float* __restrict__ h, const float* __restrict__ mems,
    const float* __restrict__ Wq, const float* __restrict__ Wk,
    const float* __restrict__ paramR,
    float* __restrict__ Rq3, float* __restrict__ Rk3)
{
    __shared__ float inT[128 * 36];
    const int tid  = threadIdx.x;
    const bool isQ = blockIdx.x < 128;
    const int  blk = isQ ? blockIdx.x : blockIdx.x - 128;
    const int row0 = blk * 32;
    const float* W   = isQ ? Wq : Wk;
    float*      out3 = isQ ? Rq3 : Rk3;

    for (int idx = tid; idx < 32 * 128; idx += 256) {
        int r = idx >> 7;
        int e = idx & 127;
        int grow = row0 + r;
        float v;
        if (isQ)               v = h[(size_t)grow * 128 + e];
        else if (grow < 4096)  v = mems[(size_t)grow * 128 + e];
        else                   v = h[(size_t)(grow - 4096) * 128 + e];
        inT[e * 36 + r] = v;
    }
    __syncthreads();

    const int col  = tid & 127;
    const int half = tid >> 7;

    float acc[16];
#pragma unroll
    for (int j = 0; j < 16; ++j) acc[j] = 0.0f;

#pragma unroll 2
    for (int e = 0; e < 128; ++e) {
        float w = W[e * 128 + col];
        const float4* ap = reinterpret_cast<const float4*>(&inT[e * 36 + half * 16]);
        float4 a0 = ap[0], a1 = ap[1], a2 = ap[2], a3 = ap[3];
        float av[16];
        av[0]=a0.x; av[1]=a0.y; av[2]=a0.z; av[3]=a0.w;
        av[4]=a1.x; av[5]=a1.y; av[6]=a1.z; av[7]=a1.w;
        av[8]=a2.x; av[9]=a2.y; av[10]=a2.z; av[11]=a2.w;
        av[12]=a3.x; av[13]=a3.y; av[14]=a3.z; av[15]=a3.w;
#pragma unroll
        for (int j = 0; j < 16; ++j) acc[j] = fmaf(av[j], w, acc[j]);
    }

    const int hh = col >> 4;
    const int d  = col & 15;
    const float Rrev = paramR[hh] * INV2PI;

#pragma unroll
    for (int j = 0; j < 16; ++j) {
        int r   = row0 + half * 16 + j;
        int tok = r >> 2;
        int b   = r & 3;
        int bh  = b * 8 + hh;
        float p = acc[j];
        float s = __builtin_amdgcn_sinf(Rrev * p);
        float c = __builtin_amdgcn_cosf(Rrev * p);
        int base = ((tok * 12 + (d >> 2)) * 32 + bh) * 4 + (d & 3);
        out3[base]        = p;
        out3[base + 512]  = s;
        out3[base + 1024] = c;
    }
}

// compile-time element pick from float4 / f32x2 pair
#define EL4(v, d) ((d) == 0 ? (v).x : (d) == 1 ? (v).y : (d) == 2 ? (v).z : (v).w)
#define ELP(a, b, d) ((d) < 2 ? (a)[(d)] : (b)[(d) - 2])

// ---------------------------------------------------------------------------
// Main kernel.
// Block = 256 threads = 4 waves; wave wv owns q-tile qb = x*16 + wv*4 (TQ=4
// q-states per lane, 192 VGPR). K-states staged into LDS in 4-token windows
// (24.6 KB), double-buffered, via global_load_lds (contiguous layout).
// Lane (kk2 = l>>5, bh = l&31) computes TQ=4 q x TK=2 k per window.
// Per output: 3 ds_read_b128 + ~56 packed-VALU slots; one rcp; min3 guard.
// ---------------------------------------------------------------------------
__global__ __launch_bounds__(256, 2) void fa_fourier_main(
    const float* __restrict__ Rq3, const float* __restrict__ Rk3,
    const float* __restrict__ paramR, float* __restrict__ out)
{
    __shared__ float4 kbuf[2][1536];   // 2 x (4 tok x 12 x 32) = 49152 B

    const int tid = threadIdx.x;
    const int wv  = tid >> 6;
    const int l   = tid & 63;
    const int kk2 = l >> 5;
    const int bh  = l & 31;
    const int bid = blockIdx.x;
    const int y   = bid & 7;           // k-chunk -> XCD (round-robin dispatch)
    const int x   = bid >> 3;          // q-block 0..63
    const int k0  = y * 256;
    const int qb  = x * 16 + wv * 4;

    const float R = paramR[bh & 7];

    // ---- q-state: 4 q x {p,s,c}[16] as f32x2[8] each (192 VGPR) ----
    f32x2 qp[4][8], qs[4][8], qc[4][8];
    {
        const float4* qsrc = reinterpret_cast<const float4*>(Rq3);
#pragma unroll
        for (int q = 0; q < 4; ++q) {
            size_t base = (size_t)(qb + q) * 384 + bh;
#pragma unroll
            for (int t = 0; t < 4; ++t) {
                float4 pv = qsrc[base + t * 32];
                float4 sv = qsrc[base + (4 + t) * 32];
                float4 cv = qsrc[base + (8 + t) * 32];
                qp[q][2*t] = (f32x2){pv.x, pv.y};  qp[q][2*t+1] = (f32x2){pv.z, pv.w};
                qs[q][2*t] = (f32x2){sv.x, sv.y};  qs[q][2*t+1] = (f32x2){sv.z, sv.w};
                qc[q][2*t] = (f32x2){cv.x, cv.y};  qc[q][2*t+1] = (f32x2){cv.z, cv.w};
            }
        }
    }

    const float4* ksrc = reinterpret_cast<const float4*>(Rk3);
    float* ob = out + ((size_t)qb * KLEN + k0 + kk2 * 2) * 32 + bh;

    // ---- stage window w into buffer parity (6 x 16B per thread) ----
    auto stage = [&](int w, int parity) {
        size_t gbase = (size_t)(k0 + w * 4) * 384;
#pragma unroll
        for (int i = 0; i < 6; ++i) {
            int fi = i * 256 + tid;
            __builtin_amdgcn_global_load_lds(
                (const __attribute__((address_space(1))) void*)(ksrc + gbase + fi),
                (__attribute__((address_space(3))) void*)(&kbuf[parity][fi]),
                16, 0, 0);
        }
    };

    stage(0, 0);

    for (int w = 0; w < 64; ++w) {
        __syncthreads();               // drains stage(w) [vmcnt(0)], fences dbuf
        if (w < 63) stage(w + 1, (w + 1) & 1);
        const float4* kb = kbuf[w & 1];

#pragma unroll
        for (int j = 0; j < 2; ++j) {
            const int kw = kk2 * 2 + j;
            const float4* kst = kb + kw * 384 + bh;   // (kw*12 + t)*32 + bh

            f32x2 UU[4], NN[4];
            float mn[4];
#pragma unroll
            for (int c = 0; c < 4; ++c) {
                float4 kpv = kst[c * 32];
                float4 ksv = kst[(4 + c) * 32];
                float4 kcv = kst[(8 + c) * 32];
                f32x2 kpa = {kpv.x, kpv.y}, kpb = {kpv.z, kpv.w};
                f32x2 ksa = {ksv.x, ksv.y}, ksb = {ksv.z, ksv.w};
                f32x2 kca = {kcv.x, kcv.y}, kcb = {kcv.z, kcv.w};
#pragma unroll
                for (int q = 0; q < 4; ++q) {
                    f32x2 ua = qp[q][2*c]   - kpa;
                    f32x2 ub = qp[q][2*c+1] - kpb;
                    f32x2 ta = qc[q][2*c]   * ksa;
                    f32x2 tb = qc[q][2*c+1] * ksb;
                    f32x2 na = __builtin_elementwise_fma(qs[q][2*c],   kca, -ta);
                    f32x2 nb = __builtin_elementwise_fma(qs[q][2*c+1], kcb, -tb);
                    f32x2 tu = ua * ub;
                    f32x2 tn = na * nb;
                    float m1 = fminf(fminf(fabsf(ua.x), fabsf(ua.y)),
                                     fminf(fabsf(ub.x), fabsf(ub.y)));
                    if (c == 0) { UU[q] = tu;  NN[q] = tn;  mn[q] = m1; }
                    else        { UU[q] *= tu; NN[q] *= tn; mn[q] = fminf(mn[q], m1); }
                }
            }

#pragma unroll
            for (int q = 0; q < 4; ++q) {
                float uu = UU[q].x * UU[q].y;
                float nn = NN[q].x * NN[q].y;
                float r  = nn * __builtin_amdgcn_rcpf(uu);
                if (__builtin_expect(mn[q] < TGUARD, 0)) {
                    // cold path: exact semantics for tiny diffs (Taylor = R to fp32
                    // precision for |u|<1e-6, ref's threshold; smooth up to TGUARD)
                    float pu = 1.0f, pn = 1.0f;
#pragma unroll
                    for (int c = 0; c < 4; ++c) {
                        float4 kpv = kst[c * 32];
                        float4 ksv = kst[(4 + c) * 32];
                        float4 kcv = kst[(8 + c) * 32];
#pragma unroll
                        for (int d = 0; d < 4; ++d) {
                            float qpd = ELP(qp[q][2*c], qp[q][2*c+1], d);
                            float qsd = ELP(qs[q][2*c], qs[q][2*c+1], d);
                            float qcd = ELP(qc[q][2*c], qc[q][2*c+1], d);
                            float u = qpd - EL4(kpv, d);
                            float n = fmaf(qsd, EL4(kcv, d), -(qcd * EL4(ksv, d)));
                            if (fabsf(u) < TGUARD) {
                                float ru = R * u;
                                n = R * fmaf(-ru * ru, 0.16666667f, 1.0f);
                                u = 1.0f;
                            }
                            pu *= u; pn *= n;
                        }
                    }
                    r = pn * __builtin_amdgcn_rcpf(pu);
                }
                __builtin_nontemporal_store(
                    fabsf(r), ob + (size_t)q * (KLEN * 32) + (w * 4 + j) * 32);
            }
        }
    }
}

extern "C" void kernel_launch(void* const* d_in, const int* in_sizes, int n_in,
                              void* d_out, int out_size, void* d_ws, size_t ws_size,
                              hipStream_t stream)
{
    const float* h    = (const float*)d_in[0];   // [1024,4,128]
    const float* mems = (const float*)d_in[1];   // [1024,4,128]
    const float* Wq   = (const float*)d_in[2];   // [128,128]
    const float* Wk   = (const float*)d_in[3];   // [128,128]
    const float* R    = (const float*)d_in[4];   // [8]
    float* out = (float*)d_out;                  // [1024,2048,4,8] fp32

    float* Rq3 = (float*)d_ws;                   // 1024*1536 floats (6 MB)
    float* Rk3 = Rq3 + (size_t)1024 * 1536;      // 2048*1536 floats (12 MB)

    fa_proj_kernel<<<dim3(384), 256, 0, stream>>>(h, mems, Wq, Wk, R, Rq3, Rk3);

    // 64 q-blocks x 8 k-chunks; bid&7 = k-chunk (XCD-pinned)
    fa_fourier_main<<<dim3(512), 256, 0, stream>>>(Rq3, Rk3, R, out);
}

// Round 4
// 307.066 us; speedup vs baseline: 1.3679x; 1.0035x over previous
//
#include <hip/hip_runtime.h>

#define QLEN 1024
#define KLEN 2048   // MLEN + QLEN

typedef float f32x2 __attribute__((ext_vector_type(2)));

static constexpr float INV2PI = 0.15915494309189535f;
static constexpr float TGUARD = 3e-5f;

// ---------------------------------------------------------------------------
// Fused projection + sincos precompute (unchanged from round 2, verified).
// Layout per token: float4 index = (tok*12 + part*4 + c)*32 + bh
//   part 0 = p, 1 = sin(R*p), 2 = cos(R*p);  c = d>>2;  elem = d&3
// ---------------------------------------------------------------------------
__global__ __launch_bounds__(256) void fa_proj_kernel(
    const float* __restrict__ h, const float* __restrict__ mems,
    const float* __restrict__ Wq, const float* __restrict__ Wk,
    const float* __restrict__ paramR,
    float* __restrict__ Rq3, float* __restrict__ Rk3)
{
    __shared__ float inT[128 * 36];
    const int tid  = threadIdx.x;
    const bool isQ = blockIdx.x < 128;
    const int  blk = isQ ? blockIdx.x : blockIdx.x - 128;
    const int row0 = blk * 32;
    const float* W   = isQ ? Wq : Wk;
    float*      out3 = isQ ? Rq3 : Rk3;

    for (int idx = tid; idx < 32 * 128; idx += 256) {
        int r = idx >> 7;
        int e = idx & 127;
        int grow = row0 + r;
        float v;
        if (isQ)               v = h[(size_t)grow * 128 + e];
        else if (grow < 4096)  v = mems[(size_t)grow * 128 + e];
        else                   v = h[(size_t)(grow - 4096) * 128 + e];
        inT[e * 36 + r] = v;
    }
    __syncthreads();

    const int col  = tid & 127;
    const int half = tid >> 7;

    float acc[16];
#pragma unroll
    for (int j = 0; j < 16; ++j) acc[j] = 0.0f;

#pragma unroll 2
    for (int e = 0; e < 128; ++e) {
        float w = W[e * 128 + col];
        const float4* ap = reinterpret_cast<const float4*>(&inT[e * 36 + half * 16]);
        float4 a0 = ap[0], a1 = ap[1], a2 = ap[2], a3 = ap[3];
        float av[16];
        av[0]=a0.x; av[1]=a0.y; av[2]=a0.z; av[3]=a0.w;
        av[4]=a1.x; av[5]=a1.y; av[6]=a1.z; av[7]=a1.w;
        av[8]=a2.x; av[9]=a2.y; av[10]=a2.z; av[11]=a2.w;
        av[12]=a3.x; av[13]=a3.y; av[14]=a3.z; av[15]=a3.w;
#pragma unroll
        for (int j = 0; j < 16; ++j) acc[j] = fmaf(av[j], w, acc[j]);
    }

    const int hh = col >> 4;
    const int d  = col & 15;
    const float Rrev = paramR[hh] * INV2PI;

#pragma unroll
    for (int j = 0; j < 16; ++j) {
        int r   = row0 + half * 16 + j;
        int tok = r >> 2;
        int b   = r & 3;
        int bh  = b * 8 + hh;
        float p = acc[j];
        float s = __builtin_amdgcn_sinf(Rrev * p);
        float c = __builtin_amdgcn_cosf(Rrev * p);
        int base = ((tok * 12 + (d >> 2)) * 32 + bh) * 4 + (d & 3);
        out3[base]        = p;
        out3[base + 512]  = s;
        out3[base + 1024] = c;
    }
}

// compile-time element pick from float4 / f32x2 pair
#define EL4(v, d) ((d) == 0 ? (v).x : (d) == 1 ? (v).y : (d) == 2 ? (v).z : (v).w)
#define ELP(a, b, d) ((d) < 2 ? (a)[(d)] : (b)[(d) - 2])

// ---------------------------------------------------------------------------
// Main kernel.
// Block = 256 threads = 4 waves; wave wv owns q-tile qb = x*16 + wv*4 (TQ=4
// q-states per lane, 192 VGPR). K-states staged into LDS in 4-token windows
// (24.6 KB), double-buffered, via global_load_lds (contiguous layout).
// Lane (kk2 = l>>5, bh = l&31) computes TQ=4 q x TK=2 k per window.
// Per output: 3 ds_read_b128 + ~56 packed-VALU slots; one rcp; min3 guard.
// ---------------------------------------------------------------------------
__global__ __launch_bounds__(256, 2) void fa_fourier_main(
    const float* __restrict__ Rq3, const float* __restrict__ Rk3,
    const float* __restrict__ paramR, float* __restrict__ out)
{
    __shared__ float4 kbuf[2][1536];   // 2 x (4 tok x 12 x 32) = 49152 B

    const int tid = threadIdx.x;
    const int wv  = tid >> 6;
    const int l   = tid & 63;
    const int kk2 = l >> 5;
    const int bh  = l & 31;
    const int bid = blockIdx.x;
    const int y   = bid & 7;           // k-chunk -> XCD (round-robin dispatch)
    const int x   = bid >> 3;          // q-block 0..63
    const int k0  = y * 256;
    const int qb  = x * 16 + wv * 4;

    const float R = paramR[bh & 7];

    // ---- q-state: 4 q x {p,s,c}[16] as f32x2[8] each (192 VGPR) ----
    f32x2 qp[4][8], qs[4][8], qc[4][8];
    {
        const float4* qsrc = reinterpret_cast<const float4*>(Rq3);
#pragma unroll
        for (int q = 0; q < 4; ++q) {
            size_t base = (size_t)(qb + q) * 384 + bh;
#pragma unroll
            for (int t = 0; t < 4; ++t) {
                float4 pv = qsrc[base + t * 32];
                float4 sv = qsrc[base + (4 + t) * 32];
                float4 cv = qsrc[base + (8 + t) * 32];
                qp[q][2*t] = (f32x2){pv.x, pv.y};  qp[q][2*t+1] = (f32x2){pv.z, pv.w};
                qs[q][2*t] = (f32x2){sv.x, sv.y};  qs[q][2*t+1] = (f32x2){sv.z, sv.w};
                qc[q][2*t] = (f32x2){cv.x, cv.y};  qc[q][2*t+1] = (f32x2){cv.z, cv.w};
            }
        }
    }

    const float4* ksrc = reinterpret_cast<const float4*>(Rk3);
    float* ob = out + ((size_t)qb * KLEN + k0 + kk2 * 2) * 32 + bh;

    // ---- stage window w into buffer parity (6 x 16B per thread) ----
    auto stage = [&](int w, int parity) {
        size_t gbase = (size_t)(k0 + w * 4) * 384;
#pragma unroll
        for (int i = 0; i < 6; ++i) {
            int fi = i * 256 + tid;
            __builtin_amdgcn_global_load_lds(
                (const __attribute__((address_space(1))) void*)(ksrc + gbase + fi),
                (__attribute__((address_space(3))) void*)(&kbuf[parity][fi]),
                16, 0, 0);
        }
    };

    stage(0, 0);

    for (int w = 0; w < 64; ++w) {
        __syncthreads();               // drains stage(w) [vmcnt(0)], fences dbuf
        if (w < 63) stage(w + 1, (w + 1) & 1);
        const float4* kb = kbuf[w & 1];

#pragma unroll
        for (int j = 0; j < 2; ++j) {
            const int kw = kk2 * 2 + j;
            const float4* kst = kb + kw * 384 + bh;   // (kw*12 + t)*32 + bh

            f32x2 UU[4], NN[4];
            float mn[4];
#pragma unroll
            for (int c = 0; c < 4; ++c) {
                float4 kpv = kst[c * 32];
                float4 ksv = kst[(4 + c) * 32];
                float4 kcv = kst[(8 + c) * 32];
                f32x2 kpa = {kpv.x, kpv.y}, kpb = {kpv.z, kpv.w};
                f32x2 ksa = {ksv.x, ksv.y}, ksb = {ksv.z, ksv.w};
                f32x2 kca = {kcv.x, kcv.y}, kcb = {kcv.z, kcv.w};
#pragma unroll
                for (int q = 0; q < 4; ++q) {
                    f32x2 ua = qp[q][2*c]   - kpa;
                    f32x2 ub = qp[q][2*c+1] - kpb;
                    f32x2 ta = qc[q][2*c]   * ksa;
                    f32x2 tb = qc[q][2*c+1] * ksb;
                    f32x2 na = __builtin_elementwise_fma(qs[q][2*c],   kca, -ta);
                    f32x2 nb = __builtin_elementwise_fma(qs[q][2*c+1], kcb, -tb);
                    f32x2 tu = ua * ub;
                    f32x2 tn = na * nb;
                    float m1 = fminf(fminf(fabsf(ua.x), fabsf(ua.y)),
                                     fminf(fabsf(ub.x), fabsf(ub.y)));
                    if (c == 0) { UU[q] = tu;  NN[q] = tn;  mn[q] = m1; }
                    else        { UU[q] *= tu; NN[q] *= tn; mn[q] = fminf(mn[q], m1); }
                }
            }

#pragma unroll
            for (int q = 0; q < 4; ++q) {
                float uu = UU[q].x * UU[q].y;
                float nn = NN[q].x * NN[q].y;
                float r  = nn * __builtin_amdgcn_rcpf(uu);
                if (__builtin_expect(mn[q] < TGUARD, 0)) {
                    // cold path: exact semantics for tiny diffs (Taylor = R to fp32
                    // precision for |u|<1e-6, ref's threshold; smooth up to TGUARD)
                    float pu = 1.0f, pn = 1.0f;
#pragma unroll
                    for (int c = 0; c < 4; ++c) {
                        float4 kpv = kst[c * 32];
                        float4 ksv = kst[(4 + c) * 32];
                        float4 kcv = kst[(8 + c) * 32];
#pragma unroll
                        for (int d = 0; d < 4; ++d) {
                            float qpd = ELP(qp[q][2*c], qp[q][2*c+1], d);
                            float qsd = ELP(qs[q][2*c], qs[q][2*c+1], d);
                            float qcd = ELP(qc[q][2*c], qc[q][2*c+1], d);
                            float u = qpd - EL4(kpv, d);
                            float n = fmaf(qsd, EL4(kcv, d), -(qcd * EL4(ksv, d)));
                            if (fabsf(u) < TGUARD) {
                                float ru = R * u;
                                n = R * fmaf(-ru * ru, 0.16666667f, 1.0f);
                                u = 1.0f;
                            }
                            pu *= u; pn *= n;
                        }
                    }
                    r = pn * __builtin_amdgcn_rcpf(pu);
                }
                __builtin_nontemporal_store(
                    fabsf(r), ob + (size_t)q * (KLEN * 32) + (w * 4 + j) * 32);
            }
        }
    }
}

extern "C" void kernel_launch(void* const* d_in, const int* in_sizes, int n_in,
                              void* d_out, int out_size, void* d_ws, size_t ws_size,
                              hipStream_t stream)
{
    const float* h    = (const float*)d_in[0];   // [1024,4,128]
    const float* mems = (const float*)d_in[1];   // [1024,4,128]
    const float* Wq   = (const float*)d_in[2];   // [128,128]
    const float* Wk   = (const float*)d_in[3];   // [128,128]
    const float* R    = (const float*)d_in[4];   // [8]
    float* out = (float*)d_out;                  // [1024,2048,4,8] fp32

    float* Rq3 = (float*)d_ws;                   // 1024*1536 floats (6 MB)
    float* Rk3 = Rq3 + (size_t)1024 * 1536;      // 2048*1536 floats (12 MB)

    fa_proj_kernel<<<dim3(384), 256, 0, stream>>>(h, mems, Wq, Wk, R, Rq3, Rk3);

    // 64 q-blocks x 8 k-chunks; bid&7 = k-chunk (XCD-pinned)
    fa_fourier_main<<<dim3(512), 256, 0, stream>>>(Rq3, Rk3, R, out);
}